// Round 1
// baseline (1045.639 us; speedup 1.0000x reference)
//
#include <hip/hip_runtime.h>

// LSTM: B=1024, T=128, H=256, C=10.
// 64 groups x 4 blocks; group = 16 batch rows, block = 64 hidden units (all 4 gates).
// Recurrent weights live in VGPRs as MFMA B-fragments for all 128 steps.
// Group-shared h double-buffer + per-block flags in d_ws (memset each launch).

#define TSTEPS  128
#define HDIM    256
#define NCLS    10
#define NGROUPS 64
#define GSIZE   4
#define BB      16

#define HBUF_SHORTS_PER_GROUP (2 * BB * HDIM)                 // 8192 bf16 = 16KB
#define HBUF_SHORTS_TOTAL     (NGROUPS * HBUF_SHORTS_PER_GROUP)
#define FLAGS_INTS_PER_GROUP  16                              // 64B-padded per group

typedef short bf16x8 __attribute__((ext_vector_type(8)));
typedef float f32x4  __attribute__((ext_vector_type(4)));

static __device__ __forceinline__ unsigned short f2bf(float f) {
    unsigned int u = __builtin_bit_cast(unsigned int, f);
    u += 0x7fffu + ((u >> 16) & 1u);                          // round-to-nearest-even
    return (unsigned short)(u >> 16);
}
static __device__ __forceinline__ float bf2f(unsigned short s) {
    return __builtin_bit_cast(float, (unsigned int)s << 16);
}
static __device__ __forceinline__ float fast_sigmoid(float x) {
    return __builtin_amdgcn_rcpf(1.0f + __expf(-x));
}
static __device__ __forceinline__ float fast_tanh(float x) {
    return 2.0f * __builtin_amdgcn_rcpf(1.0f + __expf(-2.0f * x)) - 1.0f;
}

__global__ __launch_bounds__(256, 1)
void lstm_persistent(const float* __restrict__ x,
                     const float* __restrict__ w_gx, const float* __restrict__ w_ix,
                     const float* __restrict__ w_fx, const float* __restrict__ w_ox,
                     const float* __restrict__ w_gh, const float* __restrict__ w_ih,
                     const float* __restrict__ w_fh, const float* __restrict__ w_oh,
                     const float* __restrict__ b_g,  const float* __restrict__ b_i,
                     const float* __restrict__ b_f,  const float* __restrict__ b_o,
                     const float* __restrict__ w_ph, const float* __restrict__ b_p,
                     float* __restrict__ out,
                     unsigned short* hbuf, int* flags)
{
    const int bid  = blockIdx.x;
    // XCD swizzle: group members {g} all have bid%8 == g&7 -> same XCD (heuristic,
    // correctness still guaranteed by agent-scope atomics).
    const int xcd  = bid & 7;
    const int y    = bid >> 3;
    const int g    = xcd + 8 * (y >> 2);     // group 0..63
    const int s    = y & 3;                  // member slice 0..3
    const int tid  = threadIdx.x;
    const int wave = tid >> 6;
    const int lane = tid & 63;
    const int l16  = lane & 15;
    const int lq   = lane >> 4;              // 0..3

    __shared__ float x_lds[BB * TSTEPS];     // 8KB: this group's x tile

    {
        const float* xs = x + (size_t)g * BB * TSTEPS;   // rows are contiguous: g*2048..
        for (int i = tid; i < BB * TSTEPS; i += 256) x_lds[i] = xs[i];
    }

    const int u_local = wave * 16 + l16;     // hidden unit within block slice (0..63)
    const int u_group = s * 64 + u_local;    // hidden unit within H (0..255)

    // ---- pack recurrent-weight B-fragments into registers (one-time) ----
    // B-fragment layout for mfma_f32_16x16x32_bf16: lane holds B[(lane>>4)*8+e][lane&15]
    const float* const whp[4] = {w_gh, w_ih, w_fh, w_oh};
    bf16x8 wfrag[4][8];
#pragma unroll
    for (int q = 0; q < 4; ++q) {
        const float* wp = whp[q];
#pragma unroll
        for (int kk = 0; kk < 8; ++kk) {
            bf16x8 f;
#pragma unroll
            for (int e = 0; e < 8; ++e) {
                const int k = kk * 32 + lq * 8 + e;
                f[e] = (short)f2bf(wp[k * HDIM + u_group]);
            }
            wfrag[q][kk] = f;
        }
    }
    const float* const wxp[4] = {w_gx, w_ix, w_fx, w_ox};
    const float* const bbp[4] = {b_g, b_i, b_f, b_o};
    float wx[4], bias[4];
#pragma unroll
    for (int q = 0; q < 4; ++q) { wx[q] = wxp[q][u_group]; bias[q] = bbp[q][u_group]; }

    unsigned short* hb  = hbuf + (size_t)g * HBUF_SHORTS_PER_GROUP;
    int*            flg = flags + g * FLAGS_INTS_PER_GROUP;

    float c[4] = {0.f, 0.f, 0.f, 0.f};       // cell state: 4 rows x 1 unit per lane

    for (int t = 0; t < TSTEPS; ++t) {
        // wait until all 4 members have published h^t (t=0: zeros from memset)
        if (t > 0 && tid < GSIZE) {
            while (__hip_atomic_load(&flg[tid], __ATOMIC_ACQUIRE,
                                     __HIP_MEMORY_SCOPE_AGENT) < t) {}
        }
        __syncthreads();

        const unsigned short* hsrc = hb + (t & 1) * (BB * HDIM);
        // A-fragment: lane holds h[lane&15][(lane>>4)*8+e] per 32-wide K step
        bf16x8 afrag[8];
#pragma unroll
        for (int kk = 0; kk < 8; ++kk) {
            afrag[kk] = *(const bf16x8*)(hsrc + l16 * HDIM + kk * 32 + lq * 8);
        }

        f32x4 acc[4] = {{0,0,0,0},{0,0,0,0},{0,0,0,0},{0,0,0,0}};
#pragma unroll
        for (int kk = 0; kk < 8; ++kk) {
#pragma unroll
            for (int q = 0; q < 4; ++q) {
                acc[q] = __builtin_amdgcn_mfma_f32_16x16x32_bf16(
                             afrag[kk], wfrag[q][kk], acc[q], 0, 0, 0);
            }
        }

        // epilogue: lane owns rows lq*4+j, unit u_local, all 4 gates in acc[q][j]
        unsigned short* hdst = hb + ((t + 1) & 1) * (BB * HDIM);
#pragma unroll
        for (int j = 0; j < 4; ++j) {
            const int   row = lq * 4 + j;
            const float xv  = x_lds[row * TSTEPS + t];
            const float zg = acc[0][j] + xv * wx[0] + bias[0];
            const float zi = acc[1][j] + xv * wx[1] + bias[1];
            const float zf = acc[2][j] + xv * wx[2] + bias[2];
            const float zo = acc[3][j] + xv * wx[3] + bias[3];
            const float gg = fast_tanh(zg);
            const float ii = fast_sigmoid(zi);
            const float ff = fast_sigmoid(zf);
            const float oo = fast_sigmoid(zo);
            c[j] = gg * ii + c[j] * ff;
            const float hh = fast_tanh(c[j]) * oo;
            hdst[row * HDIM + u_group] = f2bf(hh);
        }

        __syncthreads();   // emits s_waitcnt vmcnt(0): all h stores of block complete
        if (tid == 0) {
            __hip_atomic_store(&flg[s], t + 1, __ATOMIC_RELEASE,
                               __HIP_MEMORY_SCOPE_AGENT);
        }
    }

    // ---- final projection by group leader: out[g*16 .. +16][0..10) ----
    if (s == 0) {
        if (tid < GSIZE) {
            while (__hip_atomic_load(&flg[tid], __ATOMIC_ACQUIRE,
                                     __HIP_MEMORY_SCOPE_AGENT) < TSTEPS) {}
        }
        __syncthreads();
        const unsigned short* hf = hb + (TSTEPS & 1) * (BB * HDIM);  // parity 0
        for (int i = tid; i < BB * NCLS; i += 256) {
            const int r = i / NCLS, cls = i - r * NCLS;
            float a = b_p[cls];
#pragma unroll 8
            for (int u = 0; u < HDIM; ++u) {
                a += bf2f(hf[r * HDIM + u]) * w_ph[u * NCLS + cls];
            }
            out[(size_t)(g * BB + r) * NCLS + cls] = a;
        }
    }
}

extern "C" void kernel_launch(void* const* d_in, const int* in_sizes, int n_in,
                              void* d_out, int out_size, void* d_ws, size_t ws_size,
                              hipStream_t stream)
{
    const float* x    = (const float*)d_in[0];
    const float* w_gx = (const float*)d_in[1];
    const float* w_ix = (const float*)d_in[2];
    const float* w_fx = (const float*)d_in[3];
    const float* w_ox = (const float*)d_in[4];
    const float* w_gh = (const float*)d_in[5];
    const float* w_ih = (const float*)d_in[6];
    const float* w_fh = (const float*)d_in[7];
    const float* w_oh = (const float*)d_in[8];
    const float* b_g  = (const float*)d_in[9];
    const float* b_i  = (const float*)d_in[10];
    const float* b_f  = (const float*)d_in[11];
    const float* b_o  = (const float*)d_in[12];
    const float* w_ph = (const float*)d_in[13];
    const float* b_p  = (const float*)d_in[14];

    unsigned short* hbuf  = (unsigned short*)d_ws;
    int*            flags = (int*)((char*)d_ws + (size_t)HBUF_SHORTS_TOTAL * 2);
    const size_t clear_bytes = (size_t)HBUF_SHORTS_TOTAL * 2
                             + (size_t)NGROUPS * FLAGS_INTS_PER_GROUP * 4;
    // zeroes h^0 (=h0), c handled in regs, and resets flags -> deterministic per replay
    hipMemsetAsync(d_ws, 0, clear_bytes, stream);

    hipLaunchKernelGGL(lstm_persistent, dim3(256), dim3(256), 0, stream,
                       x, w_gx, w_ix, w_fx, w_ox, w_gh, w_ih, w_fh, w_oh,
                       b_g, b_i, b_f, b_o, w_ph, b_p,
                       (float*)d_out, hbuf, flags);
}

// Round 2
// 465.889 us; speedup vs baseline: 2.2444x; 2.2444x over previous
//
#include <hip/hip_runtime.h>

// LSTM: B=1024, T=128, H=256, C=10.
// 64 groups x 4 blocks; group = 16 batch rows, block = 64 hidden units (all 4 gates).
// Recurrent weights live in registers for all 128 steps.
// h exchange: RELAXED agent-scope atomics (sc0 sc1 -> Infinity-Cache served, no L2
// writeback/invalidate, unlike acquire/release which flush L2 per step).
// Ordering: producer __syncthreads (s_waitcnt vmcnt(0)) before flag store; consumer
// polls flag then loads (program order + asm memory clobber).

#define TSTEPS  128
#define HDIM    256
#define NCLS    10
#define NGROUPS 64
#define GSIZE   4
#define BB      16

#define HBUF_SHORTS_PER_GROUP (2 * BB * HDIM)                 // 8192 bf16 = 16KB
#define HBUF_SHORTS_TOTAL     (NGROUPS * HBUF_SHORTS_PER_GROUP)
#define FLAG_STRIDE           16                              // dwords: 64B line per flag
#define FLAGS_INTS_PER_GROUP  (GSIZE * FLAG_STRIDE)

typedef short bf16x8 __attribute__((ext_vector_type(8)));
typedef float f32x4  __attribute__((ext_vector_type(4)));
typedef unsigned long long u64;
typedef u64 u64x2 __attribute__((ext_vector_type(2)));

static __device__ __forceinline__ unsigned short f2bf(float f) {
    unsigned int u = __builtin_bit_cast(unsigned int, f);
    u += 0x7fffu + ((u >> 16) & 1u);                          // round-to-nearest-even
    return (unsigned short)(u >> 16);
}
static __device__ __forceinline__ float bf2f(unsigned short s) {
    return __builtin_bit_cast(float, (unsigned int)s << 16);
}
static __device__ __forceinline__ float fast_sigmoid(float x) {
    return __builtin_amdgcn_rcpf(1.0f + __expf(-x));
}
static __device__ __forceinline__ float fast_tanh(float x) {
    return 2.0f * __builtin_amdgcn_rcpf(1.0f + __expf(-2.0f * x)) - 1.0f;
}
static __device__ __forceinline__ u64 if_load64(const void* p) {
    return __hip_atomic_load((const u64*)p, __ATOMIC_RELAXED, __HIP_MEMORY_SCOPE_AGENT);
}

__global__ __launch_bounds__(256, 1)
void lstm_persistent(const float* __restrict__ x,
                     const float* __restrict__ w_gx, const float* __restrict__ w_ix,
                     const float* __restrict__ w_fx, const float* __restrict__ w_ox,
                     const float* __restrict__ w_gh, const float* __restrict__ w_ih,
                     const float* __restrict__ w_fh, const float* __restrict__ w_oh,
                     const float* __restrict__ b_g,  const float* __restrict__ b_i,
                     const float* __restrict__ b_f,  const float* __restrict__ b_o,
                     const float* __restrict__ w_ph, const float* __restrict__ b_p,
                     float* __restrict__ out,
                     unsigned short* hbuf, int* flags)
{
    const int bid  = blockIdx.x;
    // group members share bid%8 -> likely same XCD (perf heuristic only; correctness
    // comes from IF-coherent relaxed atomics).
    const int xcd  = bid & 7;
    const int y    = bid >> 3;
    const int g    = xcd + 8 * (y >> 2);     // group 0..63
    const int s    = y & 3;                  // member slice 0..3
    const int tid  = threadIdx.x;
    const int wave = tid >> 6;
    const int lane = tid & 63;
    const int l16  = lane & 15;
    const int lq   = lane >> 4;              // 0..3

    __shared__ __align__(16) float x_lds[BB * TSTEPS];   // 8KB, reused for h at the end

    {
        const float* xs = x + (size_t)g * BB * TSTEPS;
        for (int i = tid; i < BB * TSTEPS; i += 256) x_lds[i] = xs[i];
    }

    const int u_local = wave * 16 + l16;     // hidden unit within block slice (0..63)
    const int u_group = s * 64 + u_local;    // hidden unit within H (0..255)

    // ---- pack recurrent-weight B-fragments into registers (one-time) ----
    // B-fragment for mfma_f32_16x16x32_bf16: lane holds B[(lane>>4)*8+e][lane&15]
    const float* const whp[4] = {w_gh, w_ih, w_fh, w_oh};
    bf16x8 wfrag[4][8];
#pragma unroll
    for (int q = 0; q < 4; ++q) {
        const float* wp = whp[q];
#pragma unroll
        for (int kk = 0; kk < 8; ++kk) {
            bf16x8 f;
#pragma unroll
            for (int e = 0; e < 8; ++e) {
                const int k = kk * 32 + lq * 8 + e;
                f[e] = (short)f2bf(wp[k * HDIM + u_group]);
            }
            wfrag[q][kk] = f;
        }
    }
    const float* const wxp[4] = {w_gx, w_ix, w_fx, w_ox};
    const float* const bbp[4] = {b_g, b_i, b_f, b_o};
    float wx[4], bias[4];
#pragma unroll
    for (int q = 0; q < 4; ++q) { wx[q] = wxp[q][u_group]; bias[q] = bbp[q][u_group]; }

    unsigned short* hb  = hbuf + (size_t)g * HBUF_SHORTS_PER_GROUP;
    int*            flg = flags + g * FLAGS_INTS_PER_GROUP;

    float c[4] = {0.f, 0.f, 0.f, 0.f};       // cell state: 4 rows x 1 unit per lane

    __syncthreads();                          // x_lds ready

    for (int t = 0; t < TSTEPS; ++t) {
        f32x4 acc[4] = {{0,0,0,0},{0,0,0,0},{0,0,0,0},{0,0,0,0}};

        if (t > 0) {
            // per-wave poll: every lane watches one of the 4 member flags
            const int fo = (lane & 3) * FLAG_STRIDE;
            while (__hip_atomic_load(&flg[fo], __ATOMIC_RELAXED,
                                     __HIP_MEMORY_SCOPE_AGENT) < t) { }
            asm volatile("" ::: "memory");    // no load hoisting above the poll

            const unsigned short* hsrc = hb + (t & 1) * (BB * HDIM);
            bf16x8 afrag[8];
#pragma unroll
            for (int kk = 0; kk < 8; ++kk) {
                const unsigned short* p = hsrc + l16 * HDIM + kk * 32 + lq * 8;
                u64x2 v;
                v[0] = if_load64(p);
                v[1] = if_load64((const u64*)p + 1);
                afrag[kk] = __builtin_bit_cast(bf16x8, v);
            }
#pragma unroll
            for (int kk = 0; kk < 8; ++kk) {
#pragma unroll
                for (int q = 0; q < 4; ++q) {
                    acc[q] = __builtin_amdgcn_mfma_f32_16x16x32_bf16(
                                 afrag[kk], wfrag[q][kk], acc[q], 0, 0, 0);
                }
            }
        }
        // t==0: h0 = 0, so z = x*Wx + b only (also removes need to pre-zero hbuf)

        unsigned short* hdst = hb + ((t + 1) & 1) * (BB * HDIM);
#pragma unroll
        for (int j = 0; j < 4; ++j) {
            const int   row = lq * 4 + j;
            const float xv  = x_lds[row * TSTEPS + t];
            const float zg = acc[0][j] + xv * wx[0] + bias[0];
            const float zi = acc[1][j] + xv * wx[1] + bias[1];
            const float zf = acc[2][j] + xv * wx[2] + bias[2];
            const float zo = acc[3][j] + xv * wx[3] + bias[3];
            const float gg = fast_tanh(zg);
            const float ii = fast_sigmoid(zi);
            const float ff = fast_sigmoid(zf);
            const float oo = fast_sigmoid(zo);
            c[j] = gg * ii + c[j] * ff;
            const float hh = fast_tanh(c[j]) * oo;

            // pack 2 adjacent units into one dword; even l16 lanes store
            const float other = __shfl_xor(hh, 1);
            const unsigned int lo16 = (unsigned int)f2bf((l16 & 1) ? other : hh);
            const unsigned int hi16 = (unsigned int)f2bf((l16 & 1) ? hh : other);
            const unsigned int packed = lo16 | (hi16 << 16);
            if ((l16 & 1) == 0) {
                unsigned int* dp = (unsigned int*)(hdst + row * HDIM + u_group);
                __hip_atomic_store(dp, packed, __ATOMIC_RELAXED,
                                   __HIP_MEMORY_SCOPE_AGENT);
            }
        }

        __syncthreads();   // s_waitcnt vmcnt(0): all h stores reached coherence point
        if (tid == 0) {
            __hip_atomic_store(&flg[s * FLAG_STRIDE], t + 1, __ATOMIC_RELAXED,
                               __HIP_MEMORY_SCOPE_AGENT);
        }
    }

    // ---- final projection by group leader: out[g*16 .. +16][0..10) ----
    if (s == 0) {
        {
            const int fo = (tid & 3) * FLAG_STRIDE;
            while (__hip_atomic_load(&flg[fo], __ATOMIC_RELAXED,
                                     __HIP_MEMORY_SCOPE_AGENT) < TSTEPS) { }
            asm volatile("" ::: "memory");
        }
        __syncthreads();
        // copy final h (parity 0) into LDS via IF-coherent loads, then project
        unsigned short* hl = (unsigned short*)x_lds;
        const unsigned short* hf = hb;                      // parity 0 half
        for (int i = tid; i < (BB * HDIM) / 4; i += 256) {  // 1024 x u64
            ((u64*)hl)[i] = if_load64((const u64*)hf + i);
        }
        __syncthreads();
        for (int i = tid; i < BB * NCLS; i += 256) {
            const int r = i / NCLS, cls = i - r * NCLS;
            float a = b_p[cls];
#pragma unroll 8
            for (int u = 0; u < HDIM; ++u) {
                a += bf2f(hl[r * HDIM + u]) * w_ph[u * NCLS + cls];
            }
            out[(size_t)(g * BB + r) * NCLS + cls] = a;
        }
    }
}

extern "C" void kernel_launch(void* const* d_in, const int* in_sizes, int n_in,
                              void* d_out, int out_size, void* d_ws, size_t ws_size,
                              hipStream_t stream)
{
    const float* x    = (const float*)d_in[0];
    const float* w_gx = (const float*)d_in[1];
    const float* w_ix = (const float*)d_in[2];
    const float* w_fx = (const float*)d_in[3];
    const float* w_ox = (const float*)d_in[4];
    const float* w_gh = (const float*)d_in[5];
    const float* w_ih = (const float*)d_in[6];
    const float* w_fh = (const float*)d_in[7];
    const float* w_oh = (const float*)d_in[8];
    const float* b_g  = (const float*)d_in[9];
    const float* b_i  = (const float*)d_in[10];
    const float* b_f  = (const float*)d_in[11];
    const float* b_o  = (const float*)d_in[12];
    const float* w_ph = (const float*)d_in[13];
    const float* b_p  = (const float*)d_in[14];

    unsigned short* hbuf  = (unsigned short*)d_ws;
    int*            flags = (int*)((char*)d_ws + (size_t)HBUF_SHORTS_TOTAL * 2);

    // Only flags need zeroing (16KB). hbuf parity-0 is never read at t=0 (h0-term
    // is skipped), so the 2MB memset is gone.
    hipMemsetAsync(flags, 0, (size_t)NGROUPS * FLAGS_INTS_PER_GROUP * 4, stream);

    hipLaunchKernelGGL(lstm_persistent, dim3(256), dim3(256), 0, stream,
                       x, w_gx, w_ix, w_fx, w_ox, w_gh, w_ih, w_fh, w_oh,
                       b_g, b_i, b_f, b_o, w_ph, b_p,
                       (float*)d_out, hbuf, flags);
}

// Round 3
// 333.538 us; speedup vs baseline: 3.1350x; 1.3968x over previous
//
#include <hip/hip_runtime.h>

// LSTM: B=1024, T=128, H=256, C=10.
// Round 3: single-CU groups. 64 blocks x 512 threads (8 waves); block g owns batch
// rows [g*16, g*16+16) and ALL 256 hidden units x 4 gates.
// Recurrent weights: int8-quantized (q = rn(w*127)) by a pre-kernel into d_ws,
// register-resident B-fragments (128 VGPR/lane). h exchange via LDS double buffer,
// one __syncthreads per step. h carried as hi/lo residual int8 pair:
//   h ~= hq/127 + lq/(127*254)   (two i8 MFMA chains, recombined in epilogue)
// so h-quantization error ~3e-5 (bf16-grade); only weight quant (<=1/254) is coarse.

#define TSTEPS  128
#define HDIM    256
#define NCLS    10
#define BB      16          // batch rows per group
#define NBLOCKS 64
#define NTHR    512

// LDS strides
#define XSTR    132         // floats per x row (16*132*4   = 8448 B)
#define HSTR    272         // bytes per h row (16B-aligned; 4-bank row skew)
#define HBUF    (BB * HSTR) // 4352 B per parity
#define PSTR    260         // floats per proj row

typedef char  i8x16 __attribute__((ext_vector_type(16)));
typedef int   i32x4 __attribute__((ext_vector_type(4)));

#define L2E     1.4426950408889634f
#define MGC     (-2.0f * L2E)                 // tanh argument scale
#define SMG     (-2.0f * L2E / 16129.0f)      // acc->zs scale, tanh gate
#define SMS     (-1.0f * L2E / 16129.0f)      // acc->zs scale, sigmoid gates
#define INV254  (1.0f / 254.0f)

static __device__ __forceinline__ float rcpf(float x) {
    return __builtin_amdgcn_rcpf(x);
}
static __device__ __forceinline__ float exp2f_fast(float x) {
    return __builtin_amdgcn_exp2f(x);
}

// ---------------- pre-kernel: quantize + transpose Wh to int8 [gate][unit][k] ----
__global__ __launch_bounds__(64)
void pack_w(const float* __restrict__ wg, const float* __restrict__ wi,
            const float* __restrict__ wf, const float* __restrict__ wo,
            signed char* __restrict__ wq8)
{
    const int b = blockIdx.x;            // 0..1023
    const int q = b >> 8;                // gate
    const int u = b & 255;               // unit (column)
    const float* wp = (q == 0) ? wg : (q == 1) ? wi : (q == 2) ? wf : wo;
    const int t  = threadIdx.x;          // 0..63
    const int k0 = t * 4;
    unsigned int pk = 0;
#pragma unroll
    for (int i = 0; i < 4; ++i) {
        const float v = wp[(k0 + i) * HDIM + u];
        int qv = __float2int_rn(v * 127.0f);
        qv = (qv > 127) ? 127 : ((qv < -127) ? -127 : qv);
        pk |= ((unsigned int)qv & 255u) << (8 * i);
    }
    *(unsigned int*)(wq8 + ((size_t)(q * 256 + u) * 256 + k0)) = pk;
}

// ---------------- main persistent kernel ----------------------------------------
__global__ __launch_bounds__(NTHR, 2)
void lstm_lds(const float* __restrict__ x,
              const float* __restrict__ w_gx, const float* __restrict__ w_ix,
              const float* __restrict__ w_fx, const float* __restrict__ w_ox,
              const float* __restrict__ b_g,  const float* __restrict__ b_i,
              const float* __restrict__ b_f,  const float* __restrict__ b_o,
              const float* __restrict__ w_ph, const float* __restrict__ b_p,
              const signed char* __restrict__ wq8,
              float* __restrict__ out)
{
    const int g    = blockIdx.x;
    const int tid  = threadIdx.x;
    const int w    = tid >> 6;           // wave 0..7
    const int lane = tid & 63;
    const int l16  = lane & 15;
    const int lq   = lane >> 4;          // 0..3

    __shared__ float        x_lds[BB * XSTR];
    __shared__ signed char  h_hi[2 * HBUF];
    __shared__ signed char  h_lo[2 * HBUF];
    __shared__ float        proj[BB * PSTR];

    // x tile (16 rows x 128 steps)
    {
        const float* xs = x + (size_t)g * BB * TSTEPS;
        for (int i = tid; i < BB * TSTEPS; i += NTHR) {
            const int r = i >> 7, tt = i & 127;
            x_lds[r * XSTR + tt] = xs[i];
        }
    }

    // ---- register-resident int8 B-fragments -------------------------------------
    // wave w owns units u = w*32 + ut*16 + l16 (ut=0,1), all 4 gates.
    // fragment element e of lane (l16,lq), chunk kk: B[k = kk*64+lq*16+e][u]
    i8x16 wfr[4][2][4];
#pragma unroll
    for (int q = 0; q < 4; ++q)
#pragma unroll
        for (int ut = 0; ut < 2; ++ut) {
            const int u = w * 32 + ut * 16 + l16;
#pragma unroll
            for (int kk = 0; kk < 4; ++kk) {
                const signed char* p = wq8 + ((size_t)(q * 256 + u) * 256)
                                           + kk * 64 + lq * 16;
                wfr[q][ut][kk] = *(const i8x16*)p;
            }
        }

    const float* const wxp[4] = {w_gx, w_ix, w_fx, w_ox};
    const float* const bbp[4] = {b_g, b_i, b_f, b_o};
    float wxm[4][2], bm[4][2];
#pragma unroll
    for (int q = 0; q < 4; ++q)
#pragma unroll
        for (int ut = 0; ut < 2; ++ut) {
            const int u = w * 32 + ut * 16 + l16;
            const float m = (q == 0) ? MGC : (-L2E);
            wxm[q][ut] = wxp[q][u] * m;
            bm[q][ut]  = bbp[q][u] * m;
        }

    float c[2][4] = {{0.f,0.f,0.f,0.f},{0.f,0.f,0.f,0.f}};

    __syncthreads();

    for (int t = 0; t < TSTEPS; ++t) {
        i8x16 ah[4], al[4];
        if (t > 0) {
            const signed char* hs_hi = h_hi + (t & 1) * HBUF + l16 * HSTR;
            const signed char* hs_lo = h_lo + (t & 1) * HBUF + l16 * HSTR;
#pragma unroll
            for (int kk = 0; kk < 4; ++kk) {
                ah[kk] = *(const i8x16*)(hs_hi + kk * 64 + lq * 16);
                al[kk] = *(const i8x16*)(hs_lo + kk * 64 + lq * 16);
            }
        }

        const int p1 = (t + 1) & 1;
        signed char* hd_hi = h_hi + p1 * HBUF;
        signed char* hd_lo = h_lo + p1 * HBUF;

#pragma unroll
        for (int ut = 0; ut < 2; ++ut) {
            i32x4 a1[4] = {{0,0,0,0},{0,0,0,0},{0,0,0,0},{0,0,0,0}};
            i32x4 a2[4] = {{0,0,0,0},{0,0,0,0},{0,0,0,0},{0,0,0,0}};
            if (t > 0) {
#pragma unroll
                for (int kk = 0; kk < 4; ++kk)
#pragma unroll
                    for (int q = 0; q < 4; ++q) {
                        a1[q] = __builtin_amdgcn_mfma_i32_16x16x64_i8(
                                    __builtin_bit_cast(i32x4, ah[kk]),
                                    __builtin_bit_cast(i32x4, wfr[q][ut][kk]),
                                    a1[q], 0, 0, 0);
                        a2[q] = __builtin_amdgcn_mfma_i32_16x16x64_i8(
                                    __builtin_bit_cast(i32x4, al[kk]),
                                    __builtin_bit_cast(i32x4, wfr[q][ut][kk]),
                                    a2[q], 0, 0, 0);
                    }
            }
            const int u = w * 32 + ut * 16 + l16;
#pragma unroll
            for (int j = 0; j < 4; ++j) {
                const int   row = lq * 4 + j;
                const float xv  = x_lds[row * XSTR + t];
                // dequant: acc = a1 + a2/254 ; zs = acc*sm + (xv*wxm + bm)
                const float f0 = (float)a1[0][j] + (float)a2[0][j] * INV254;
                const float f1 = (float)a1[1][j] + (float)a2[1][j] * INV254;
                const float f2 = (float)a1[2][j] + (float)a2[2][j] * INV254;
                const float f3 = (float)a1[3][j] + (float)a2[3][j] * INV254;
                const float zs0 = __builtin_fmaf(f0, SMG, __builtin_fmaf(xv, wxm[0][ut], bm[0][ut]));
                const float zs1 = __builtin_fmaf(f1, SMS, __builtin_fmaf(xv, wxm[1][ut], bm[1][ut]));
                const float zs2 = __builtin_fmaf(f2, SMS, __builtin_fmaf(xv, wxm[2][ut], bm[2][ut]));
                const float zs3 = __builtin_fmaf(f3, SMS, __builtin_fmaf(xv, wxm[3][ut], bm[3][ut]));
                const float gg = 2.0f * rcpf(1.0f + exp2f_fast(zs0)) - 1.0f;  // tanh
                const float ii = rcpf(1.0f + exp2f_fast(zs1));                // sigmoid
                const float ff = rcpf(1.0f + exp2f_fast(zs2));
                const float oo = rcpf(1.0f + exp2f_fast(zs3));
                const float cc = __builtin_fmaf(c[ut][j], ff, gg * ii);
                c[ut][j] = cc;
                const float tc = 2.0f * rcpf(1.0f + exp2f_fast(cc * MGC)) - 1.0f;
                const float hh = tc * oo;
                // hi/lo residual quantization: h ~= hq/127 + lqv/(127*254)
                const float fq  = hh * 127.0f;
                const int   hq  = __float2int_rn(fq);
                const float er  = fq - (float)hq;
                const int   lqv = __float2int_rn(er * 254.0f);
                hd_hi[row * HSTR + u] = (signed char)hq;
                hd_lo[row * HSTR + u] = (signed char)lqv;
                if (t == TSTEPS - 1) proj[row * PSTR + u] = hh;
            }
        }
        __syncthreads();
    }

    // ---- final projection: out[g*16 + r][cls], 16x10 ----------------------------
    if (tid < BB * NCLS) {
        const int r = tid / NCLS, cls = tid - r * NCLS;
        float a = b_p[cls];
#pragma unroll 8
        for (int u = 0; u < HDIM; ++u) {
            a = __builtin_fmaf(proj[r * PSTR + u], w_ph[u * NCLS + cls], a);
        }
        out[(size_t)(g * BB + r) * NCLS + cls] = a;
    }
}

extern "C" void kernel_launch(void* const* d_in, const int* in_sizes, int n_in,
                              void* d_out, int out_size, void* d_ws, size_t ws_size,
                              hipStream_t stream)
{
    const float* x    = (const float*)d_in[0];
    const float* w_gx = (const float*)d_in[1];
    const float* w_ix = (const float*)d_in[2];
    const float* w_fx = (const float*)d_in[3];
    const float* w_ox = (const float*)d_in[4];
    const float* w_gh = (const float*)d_in[5];
    const float* w_ih = (const float*)d_in[6];
    const float* w_fh = (const float*)d_in[7];
    const float* w_oh = (const float*)d_in[8];
    const float* b_g  = (const float*)d_in[9];
    const float* b_i  = (const float*)d_in[10];
    const float* b_f  = (const float*)d_in[11];
    const float* b_o  = (const float*)d_in[12];
    const float* w_ph = (const float*)d_in[13];
    const float* b_p  = (const float*)d_in[14];

    signed char* wq8 = (signed char*)d_ws;   // 4*256*256 = 256 KB

    hipLaunchKernelGGL(pack_w, dim3(1024), dim3(64), 0, stream,
                       w_gh, w_ih, w_fh, w_oh, wq8);

    hipLaunchKernelGGL(lstm_lds, dim3(NBLOCKS), dim3(NTHR), 0, stream,
                       x, w_gx, w_ix, w_fx, w_ox,
                       b_g, b_i, b_f, b_o, w_ph, b_p,
                       wq8, (float*)d_out);
}